// Round 6
// baseline (190.060 us; speedup 1.0000x reference)
//
#include <hip/hip_runtime.h>
#include <math.h>

#define B_ 8
#define T_ 100
#define S_ 400
#define H_ 256
#define BT_ (B_ * T_)
#define MAXL 30.0f
#define K_EXP 2.885390081777927f   // 2*log2(e): exp2(K*z) = e^(2z)

#define AF_OFF (BT_ * H_)
#define LOSS_OFF (BT_ * H_ + BT_ * S_)

// ws layout (floats)
#define WHT_OFF 0                        // WhT [B][H][S] (pre-scaled by K_EXP)
#define WSB_OFF (B_ * H_ * S_)           // Wsb [BT][H] = K*(dec@W_s + b_attn)
#define AT_OFF (WSB_OFF + BT_ * H_)      // A^T / cov^T [B][S][T] (in-place scan)

__device__ __forceinline__ float wave_sum(float p) {
#pragma unroll
    for (int off = 32; off; off >>= 1) p += __shfl_xor(p, off, 64);
    return p;
}

__device__ __forceinline__ float wave_max(float p) {
#pragma unroll
    for (int off = 32; off; off >>= 1) p = fmaxf(p, __shfl_xor(p, off, 64));
    return p;
}

// ---------------- K1: WhT = K*(enc@W_h)^T, Wsb = K*(dec@W_s + b_attn) --------
#define ROWS 8
__global__ __launch_bounds__(256) void k_gemm(
    const float* __restrict__ dec, const float* __restrict__ enc,
    const float* __restrict__ W_h, const float* __restrict__ W_s,
    const float* __restrict__ b_attn,
    float* __restrict__ WhT, float* __restrict__ Wsb) {
    const int tid = threadIdx.x;          // output h
    const int blk = blockIdx.x;
    const int NB_ENC = (B_ * S_) / ROWS;  // 400

    float acc[ROWS];
#pragma unroll
    for (int r = 0; r < ROWS; ++r) acc[r] = 0.f;

    if (blk < NB_ENC) {
        const int r0 = blk * ROWS;            // global enc row; 8 rows same b
        const int b = r0 / S_, s0 = r0 - b * S_;
        const float* in = enc + (size_t)r0 * H_;   // block-uniform -> s_loads
        const float* Wp = W_h + tid;
#pragma unroll 4
        for (int h = 0; h < H_; ++h) {
            float w = Wp[(size_t)h * H_];
#pragma unroll
            for (int r = 0; r < ROWS; ++r)
                acc[r] = fmaf(in[r * H_ + h], w, acc[r]);
        }
        float* o = WhT + ((size_t)b * H_ + tid) * S_ + s0;
#pragma unroll
        for (int r = 0; r < ROWS; ++r) o[r] = K_EXP * acc[r];
    } else {
        const int bt0 = (blk - NB_ENC) * ROWS;
        const float* in = dec + (size_t)bt0 * H_;
        const float* Wp = W_s + tid;
        const float bias = b_attn[tid];
#pragma unroll 4
        for (int h = 0; h < H_; ++h) {
            float w = Wp[(size_t)h * H_];
#pragma unroll
            for (int r = 0; r < ROWS; ++r)
                acc[r] = fmaf(in[r * H_ + h], w, acc[r]);
        }
#pragma unroll
        for (int r = 0; r < ROWS; ++r)
            Wsb[(size_t)(bt0 + r) * H_ + tid] = K_EXP * (acc[r] + bias);
    }
}

// ---------------- K2: prelim logits + softmax -> A^T -------------------------
// lane = s (2 per thread). h-invariants are wave-uniform -> SGPR s_loads.
__global__ __launch_bounds__(256) void k_prelim(
    const float* __restrict__ WhT, const float* __restrict__ Wsb,
    const float* __restrict__ v,
    const unsigned char* __restrict__ mask,
    float* __restrict__ At) {
    __shared__ float red[16];
    const int blk = blockIdx.x;
    const int b = blk & 7;
    const int t = blk >> 3;
    const int bt = b * T_ + t;
    const int tid = threadIdx.x;
    const int lane = tid & 63;
    const int wid = tid >> 6;   // 0..3
    const int s0 = 2 * tid;
    const bool act = (s0 < S_);

    // sum(v) once per block (logit = sumv - 2*sum(v[h]*r[h]))
    float sv = wave_sum(v[tid]);
    if (lane == 0) red[wid] = sv;
    __syncthreads();
    const float sumv = (red[0] + red[1]) + (red[2] + red[3]);

    const float* Wsr = Wsb + (size_t)bt * H_;   // uniform -> s_load
    float acc0 = 0.f, acc1 = 0.f;
    if (act) {
        const float* wrow = WhT + (size_t)b * H_ * S_ + s0;
#pragma unroll 8
        for (int h = 0; h < H_; ++h) {
            float2 w = *reinterpret_cast<const float2*>(wrow + (size_t)h * S_);
            const float sb = Wsr[h];
            const float vh = v[h];
            float r0 = __builtin_amdgcn_rcpf(__builtin_amdgcn_exp2f(w.x + sb) + 1.0f);
            float r1 = __builtin_amdgcn_rcpf(__builtin_amdgcn_exp2f(w.y + sb) + 1.0f);
            acc0 = fmaf(r0, vh, acc0);
            acc1 = fmaf(r1, vh, acc1);
        }
    }

    float e0 = -INFINITY, e1 = -INFINITY;
    if (act) {
        const unsigned char* mb = mask + (size_t)b * S_;
        e0 = fminf(fmaxf(sumv - 2.f * acc0, -MAXL), MAXL);
        e1 = fminf(fmaxf(sumv - 2.f * acc1, -MAXL), MAXL);
        if (mb[s0]) e0 = -INFINITY;
        if (mb[s0 + 1]) e1 = -INFINITY;
    }

    float mx = wave_max(fmaxf(e0, e1));
    if (lane == 0) red[8 + wid] = mx;
    __syncthreads();
    mx = fmaxf(fmaxf(red[8], red[9]), fmaxf(red[10], red[11]));

    float p0 = act ? __expf(e0 - mx) : 0.f;
    float p1 = act ? __expf(e1 - mx) : 0.f;
    float sum = wave_sum(p0 + p1);
    if (lane == 0) red[12 + wid] = sum;
    __syncthreads();
    sum = (red[12] + red[13]) + (red[14] + red[15]);
    const float inv = __builtin_amdgcn_rcpf(sum);

    if (act) {
        float* Ar = At + ((size_t)b * S_ + s0) * T_ + t;
        Ar[0] = p0 * inv;        // At[b][s0][t]
        Ar[T_] = p1 * inv;       // At[b][s0+1][t]
    }
}

// ---------------- K3: in-place exclusive scan over t (contiguous rows) -------
__global__ __launch_bounds__(256) void k_cumsum(float* __restrict__ At,
                                                float* __restrict__ out) {
    const int idx = blockIdx.x * 256 + threadIdx.x;  // b*S + s
    if (idx == 0) out[LOSS_OFF] = 0.f;
    if (idx >= B_ * S_) return;
    float4* row = reinterpret_cast<float4*>(At + (size_t)idx * T_);
    float run = 0.f;
#pragma unroll
    for (int i = 0; i < T_ / 4; ++i) {
        float4 x = row[i];
        float4 o;
        o.x = run; run += x.x;
        o.y = run; run += x.y;
        o.z = run; run += x.z;
        o.w = run; run += x.w;
        row[i] = o;
    }
}

// ---------------- K4: final logits + softmax + context + loss ----------------
__global__ __launch_bounds__(256) void k_final(
    const float* __restrict__ WhT, const float* __restrict__ Wsb,
    const float* __restrict__ v, const float* __restrict__ w_c,
    const float* __restrict__ covT,
    const unsigned char* __restrict__ mask,
    const float* __restrict__ enc,
    float* __restrict__ out) {
    __shared__ float e_lds[S_];
    __shared__ float red[16];
    const int blk = blockIdx.x;
    const int b = blk & 7;
    const int t = blk >> 3;
    const int bt = b * T_ + t;
    const int tid = threadIdx.x;
    const int lane = tid & 63;
    const int wid = tid >> 6;
    const int s0 = 2 * tid;
    const bool act = (s0 < S_);

    float sv = wave_sum(v[tid]);
    if (lane == 0) red[wid] = sv;
    __syncthreads();
    const float sumv = (red[0] + red[1]) + (red[2] + red[3]);

    float c0 = 0.f, c1 = 0.f;
    if (act) {
        const float* cp = covT + ((size_t)b * S_ + s0) * T_ + t;
        c0 = cp[0];
        c1 = cp[T_];
    }
    const float ck0 = K_EXP * c0, ck1 = K_EXP * c1;

    const float* Wsr = Wsb + (size_t)bt * H_;
    float acc0 = 0.f, acc1 = 0.f;
    if (act) {
        const float* wrow = WhT + (size_t)b * H_ * S_ + s0;
#pragma unroll 8
        for (int h = 0; h < H_; ++h) {
            float2 w = *reinterpret_cast<const float2*>(wrow + (size_t)h * S_);
            const float sb = Wsr[h];
            const float wch = w_c[h];
            const float vh = v[h];
            float a0 = fmaf(ck0, wch, w.x + sb);
            float a1 = fmaf(ck1, wch, w.y + sb);
            float r0 = __builtin_amdgcn_rcpf(__builtin_amdgcn_exp2f(a0) + 1.0f);
            float r1 = __builtin_amdgcn_rcpf(__builtin_amdgcn_exp2f(a1) + 1.0f);
            acc0 = fmaf(r0, vh, acc0);
            acc1 = fmaf(r1, vh, acc1);
        }
    }

    float e0 = -INFINITY, e1 = -INFINITY;
    if (act) {
        const unsigned char* mb = mask + (size_t)b * S_;
        e0 = fminf(fmaxf(sumv - 2.f * acc0, -MAXL), MAXL);
        e1 = fminf(fmaxf(sumv - 2.f * acc1, -MAXL), MAXL);
        if (mb[s0]) e0 = -INFINITY;
        if (mb[s0 + 1]) e1 = -INFINITY;
    }

    float mx = wave_max(fmaxf(e0, e1));
    if (lane == 0) red[8 + wid] = mx;
    __syncthreads();
    mx = fmaxf(fmaxf(red[8], red[9]), fmaxf(red[10], red[11]));

    float p0 = act ? __expf(e0 - mx) : 0.f;
    float p1 = act ? __expf(e1 - mx) : 0.f;
    float sum = wave_sum(p0 + p1);
    if (lane == 0) red[12 + wid] = sum;
    __syncthreads();
    sum = (red[12] + red[13]) + (red[14] + red[15]);
    const float inv = __builtin_amdgcn_rcpf(sum);

    const float a0 = p0 * inv, a1 = p1 * inv;

    // coverage-loss partial (registers only)
    float lp = act ? (fminf(a0, c0) + fminf(a1, c1)) : 0.f;
    lp = wave_sum(lp);
    if (lane == 0) red[4 + wid] = lp;

    if (act) {
        e_lds[s0] = a0;
        e_lds[s0 + 1] = a1;
        *reinterpret_cast<float2*>(out + AF_OFF + (size_t)bt * S_ + s0) =
            make_float2(a0, a1);
    }
    __syncthreads();

    if (tid == 0) {
        float tot = (red[4] + red[5]) + (red[6] + red[7]);
        atomicAdd(out + LOSS_OFF, tot * (1.0f / (B_ * T_)));
    }

    // context[b,t,h] = sum_s A[s]*enc[b,s,h]; thread = h, 4 chains
    const float* eb = enc + (size_t)b * S_ * H_ + tid;
    float ca = 0.f, cb = 0.f, cc = 0.f, cd = 0.f;
#pragma unroll 2
    for (int j = 0; j < S_; j += 4) {
        ca = fmaf(e_lds[j], eb[(size_t)j * H_], ca);
        cb = fmaf(e_lds[j + 1], eb[(size_t)(j + 1) * H_], cb);
        cc = fmaf(e_lds[j + 2], eb[(size_t)(j + 2) * H_], cc);
        cd = fmaf(e_lds[j + 3], eb[(size_t)(j + 3) * H_], cd);
    }
    out[(size_t)bt * H_ + tid] = (ca + cb) + (cc + cd);
}

extern "C" void kernel_launch(void* const* d_in, const int* in_sizes, int n_in,
                              void* d_out, int out_size, void* d_ws, size_t ws_size,
                              hipStream_t stream) {
    const float* dec = (const float*)d_in[0];
    const float* enc = (const float*)d_in[1];
    const unsigned char* mask = (const unsigned char*)d_in[2];
    const float* W_h = (const float*)d_in[3];
    const float* W_s = (const float*)d_in[4];
    const float* w_c = (const float*)d_in[5];
    const float* v = (const float*)d_in[6];
    const float* b_attn = (const float*)d_in[7];

    float* out = (float*)d_out;
    float* ws = (float*)d_ws;
    float* WhT = ws + WHT_OFF;
    float* Wsb = ws + WSB_OFF;
    float* At = ws + AT_OFF;   // A^T, scanned in place -> cov^T

    const int nb_gemm = (B_ * S_) / ROWS + BT_ / ROWS;  // 400 + 100
    k_gemm<<<nb_gemm, 256, 0, stream>>>(dec, enc, W_h, W_s, b_attn, WhT, Wsb);
    k_prelim<<<BT_, 256, 0, stream>>>(WhT, Wsb, v, mask, At);
    k_cumsum<<<(B_ * S_ + 255) / 256, 256, 0, stream>>>(At, out);
    k_final<<<BT_, 256, 0, stream>>>(WhT, Wsb, v, w_c, At, mask, enc, out);
}

// Round 7
// 163.816 us; speedup vs baseline: 1.1602x; 1.1602x over previous
//
#include <hip/hip_runtime.h>
#include <math.h>

#define B_ 8
#define T_ 100
#define S_ 400
#define H_ 256
#define BT_ (B_ * T_)
#define MAXL 30.0f
#define K_EXP 2.885390081777927f   // 2*log2(e): exp2(K*z) = e^(2z)

#define AF_OFF (BT_ * H_)
#define LOSS_OFF (BT_ * H_ + BT_ * S_)

// ws layout (floats)
#define WHT_OFF 0                        // WhT [B][H][S] (pre-scaled by K_EXP)
#define WSB_OFF (B_ * H_ * S_)           // Wsb [BT][H] = K*(dec@W_s + b_attn)
#define ACOV_OFF (WSB_OFF + BT_ * H_)    // A / cov [BT][S] (in-place scan)

__device__ __forceinline__ float wave_sum(float p) {
#pragma unroll
    for (int off = 32; off; off >>= 1) p += __shfl_xor(p, off, 64);
    return p;
}

__device__ __forceinline__ float wave_max(float p) {
#pragma unroll
    for (int off = 32; off; off >>= 1) p = fmaxf(p, __shfl_xor(p, off, 64));
    return p;
}

// ---------------- K1: WhT = K*(enc@W_h)^T, Wsb = K*(dec@W_s + b_attn) --------
#define ROWS 4
__global__ __launch_bounds__(256) void k_gemm(
    const float* __restrict__ dec, const float* __restrict__ enc,
    const float* __restrict__ W_h, const float* __restrict__ W_s,
    const float* __restrict__ b_attn,
    float* __restrict__ WhT, float* __restrict__ Wsb) {
    const int tid = threadIdx.x;          // output h
    const int blk = blockIdx.x;
    const int NB_ENC = (B_ * S_) / ROWS;  // 800

    float a0 = 0.f, a1 = 0.f, a2 = 0.f, a3 = 0.f;

    if (blk < NB_ENC) {
        const int r0 = blk * ROWS;            // 4 enc rows, same b
        const int b = r0 / S_, s0 = r0 - b * S_;
        const float* in = enc + (size_t)r0 * H_;   // block-uniform -> s_loads
        const float* Wp = W_h + tid;
#pragma unroll 8
        for (int h = 0; h < H_; ++h) {
            float w = Wp[(size_t)h * H_];
            a0 = fmaf(in[h], w, a0);
            a1 = fmaf(in[H_ + h], w, a1);
            a2 = fmaf(in[2 * H_ + h], w, a2);
            a3 = fmaf(in[3 * H_ + h], w, a3);
        }
        float* o = WhT + ((size_t)b * H_ + tid) * S_ + s0;
        o[0] = K_EXP * a0;
        o[1] = K_EXP * a1;
        o[2] = K_EXP * a2;
        o[3] = K_EXP * a3;
    } else {
        const int bt0 = (blk - NB_ENC) * ROWS;
        const float* in = dec + (size_t)bt0 * H_;
        const float* Wp = W_s + tid;
        const float bias = b_attn[tid];
#pragma unroll 8
        for (int h = 0; h < H_; ++h) {
            float w = Wp[(size_t)h * H_];
            a0 = fmaf(in[h], w, a0);
            a1 = fmaf(in[H_ + h], w, a1);
            a2 = fmaf(in[2 * H_ + h], w, a2);
            a3 = fmaf(in[3 * H_ + h], w, a3);
        }
        Wsb[(size_t)(bt0 + 0) * H_ + tid] = K_EXP * (a0 + bias);
        Wsb[(size_t)(bt0 + 1) * H_ + tid] = K_EXP * (a1 + bias);
        Wsb[(size_t)(bt0 + 2) * H_ + tid] = K_EXP * (a2 + bias);
        Wsb[(size_t)(bt0 + 3) * H_ + tid] = K_EXP * (a3 + bias);
    }
}

// ---------------- K2: prelim logits + softmax -> A [bt][s] -------------------
// 512 threads, lane = s. h-invariants (Wsb row, v) are wave-uniform -> SGPRs.
__global__ __launch_bounds__(512) void k_prelim(
    const float* __restrict__ WhT, const float* __restrict__ Wsb,
    const float* __restrict__ v,
    const unsigned char* __restrict__ mask,
    float* __restrict__ A) {
    __shared__ float red[16];
    const int blk = blockIdx.x;
    const int b = blk & 7;
    const int t = blk >> 3;
    const int bt = b * T_ + t;
    const int tid = threadIdx.x;
    const int lane = tid & 63;
    const int wid = tid >> 6;   // 0..7
    const int s = tid;
    const bool act = (s < S_);

    // sum(v): each wave reduces v via float4-per-lane butterfly (all lanes get it)
    const float4 vv4 = *reinterpret_cast<const float4*>(v + 4 * lane);
    const float sumv = wave_sum((vv4.x + vv4.y) + (vv4.z + vv4.w));

    const float* Wsr = Wsb + (size_t)bt * H_;   // uniform -> s_load
    float acc = 0.f;
    if (act) {
        const float* wcol = WhT + (size_t)b * H_ * S_ + s;
#pragma unroll 8
        for (int h = 0; h < H_; ++h) {
            float w = wcol[(size_t)h * S_];
            float r = __builtin_amdgcn_rcpf(__builtin_amdgcn_exp2f(w + Wsr[h]) + 1.0f);
            acc = fmaf(r, v[h], acc);
        }
    }

    float e = -INFINITY;
    if (act) {
        e = fminf(fmaxf(sumv - 2.f * acc, -MAXL), MAXL);
        if (mask[(size_t)b * S_ + s]) e = -INFINITY;
    }

    float mx = wave_max(e);
    if (lane == 0) red[wid] = mx;
    __syncthreads();
    mx = fmaxf(fmaxf(fmaxf(red[0], red[1]), fmaxf(red[2], red[3])),
               fmaxf(fmaxf(red[4], red[5]), fmaxf(red[6], red[7])));

    float p = act ? __expf(e - mx) : 0.f;
    float sum = wave_sum(p);
    if (lane == 0) red[8 + wid] = sum;
    __syncthreads();
    sum = ((red[8] + red[9]) + (red[10] + red[11])) +
          ((red[12] + red[13]) + (red[14] + red[15]));
    const float inv = __builtin_amdgcn_rcpf(sum);

    if (act) A[(size_t)bt * S_ + s] = p * inv;
}

// ---------------- K3: in-place exclusive scan over t; zero loss --------------
__global__ __launch_bounds__(64) void k_cumsum(float* __restrict__ A,
                                               float* __restrict__ out) {
    const int idx = blockIdx.x * 64 + threadIdx.x;  // b*S + s
    if (idx == 0) out[LOSS_OFF] = 0.f;
    if (idx >= B_ * S_) return;
    const int b = idx / S_;
    const int s = idx - b * S_;
    float* col = A + (size_t)b * T_ * S_ + s;
    float run = 0.f;
#pragma unroll 10
    for (int t = 0; t < T_; ++t) {
        float a = col[(size_t)t * S_];
        col[(size_t)t * S_] = run;  // cov_shifted
        run += a;
    }
}

// ---------------- K4: final logits + softmax + context + loss ----------------
__global__ __launch_bounds__(512) void k_final(
    const float* __restrict__ WhT, const float* __restrict__ Wsb,
    const float* __restrict__ v, const float* __restrict__ w_c,
    const float* __restrict__ cov,
    const unsigned char* __restrict__ mask,
    const float* __restrict__ enc,
    float* __restrict__ out) {
    __shared__ float e_lds[S_];
    __shared__ float ctx_part[H_];
    __shared__ float red[16];
    const int blk = blockIdx.x;
    const int b = blk & 7;
    const int t = blk >> 3;
    const int bt = b * T_ + t;
    const int tid = threadIdx.x;
    const int lane = tid & 63;
    const int wid = tid >> 6;
    const int s = tid;
    const bool act = (s < S_);

    const float4 vv4 = *reinterpret_cast<const float4*>(v + 4 * lane);
    const float sumv = wave_sum((vv4.x + vv4.y) + (vv4.z + vv4.w));

    float c = 0.f;
    if (act) c = cov[(size_t)bt * S_ + s];      // coalesced
    const float ck = K_EXP * c;

    const float* Wsr = Wsb + (size_t)bt * H_;
    float acc = 0.f;
    if (act) {
        const float* wcol = WhT + (size_t)b * H_ * S_ + s;
#pragma unroll 8
        for (int h = 0; h < H_; ++h) {
            float w = wcol[(size_t)h * S_];
            float arg = fmaf(ck, w_c[h], w + Wsr[h]);
            float r = __builtin_amdgcn_rcpf(__builtin_amdgcn_exp2f(arg) + 1.0f);
            acc = fmaf(r, v[h], acc);
        }
    }

    float e = -INFINITY;
    if (act) {
        e = fminf(fmaxf(sumv - 2.f * acc, -MAXL), MAXL);
        if (mask[(size_t)b * S_ + s]) e = -INFINITY;
    }

    float mx = wave_max(e);
    if (lane == 0) red[wid] = mx;
    __syncthreads();
    mx = fmaxf(fmaxf(fmaxf(red[0], red[1]), fmaxf(red[2], red[3])),
               fmaxf(fmaxf(red[4], red[5]), fmaxf(red[6], red[7])));

    float p = act ? __expf(e - mx) : 0.f;
    float sum = wave_sum(p);
    if (lane == 0) red[8 + wid] = sum;
    __syncthreads();
    sum = ((red[8] + red[9]) + (red[10] + red[11])) +
          ((red[12] + red[13]) + (red[14] + red[15]));
    const float inv = __builtin_amdgcn_rcpf(sum);

    const float a = act ? p * inv : 0.f;

    // coverage-loss partial (registers only)
    float lp = act ? fminf(a, c) : 0.f;
    lp = wave_sum(lp);
    if (lane == 0) red[wid] = lp;

    if (act) {
        e_lds[s] = a;
        out[AF_OFF + (size_t)bt * S_ + s] = a;
    }
    __syncthreads();

    if (tid == 0) {
        float tot = ((red[0] + red[1]) + (red[2] + red[3])) +
                    ((red[4] + red[5]) + (red[6] + red[7]));
        atomicAdd(out + LOSS_OFF, tot * (1.0f / (B_ * T_)));
    }

    // context[b,t,h] = sum_s A[s]*enc[b,s,h]; 2 threads per h, half of s each
    const int h = tid & (H_ - 1);
    const int half = tid >> 8;           // 0 or 1
    const int s0 = half * (S_ / 2);      // 0 or 200
    const float* eb = enc + ((size_t)b * S_ + s0) * H_ + h;
    float ca = 0.f, cb = 0.f, cc = 0.f, cd = 0.f;
#pragma unroll 5
    for (int j = 0; j < S_ / 2; j += 4) {
        ca = fmaf(e_lds[s0 + j], eb[(size_t)j * H_], ca);
        cb = fmaf(e_lds[s0 + j + 1], eb[(size_t)(j + 1) * H_], cb);
        cc = fmaf(e_lds[s0 + j + 2], eb[(size_t)(j + 2) * H_], cc);
        cd = fmaf(e_lds[s0 + j + 3], eb[(size_t)(j + 3) * H_], cd);
    }
    if (half == 0) ctx_part[h] = (ca + cb) + (cc + cd);
    __syncthreads();
    if (half == 1) out[(size_t)bt * H_ + h] = ctx_part[h] + (ca + cb) + (cc + cd);
}

extern "C" void kernel_launch(void* const* d_in, const int* in_sizes, int n_in,
                              void* d_out, int out_size, void* d_ws, size_t ws_size,
                              hipStream_t stream) {
    const float* dec = (const float*)d_in[0];
    const float* enc = (const float*)d_in[1];
    const unsigned char* mask = (const unsigned char*)d_in[2];
    const float* W_h = (const float*)d_in[3];
    const float* W_s = (const float*)d_in[4];
    const float* w_c = (const float*)d_in[5];
    const float* v = (const float*)d_in[6];
    const float* b_attn = (const float*)d_in[7];

    float* out = (float*)d_out;
    float* ws = (float*)d_ws;
    float* WhT = ws + WHT_OFF;
    float* Wsb = ws + WSB_OFF;
    float* Acov = ws + ACOV_OFF;

    const int nb_gemm = (B_ * S_) / ROWS + BT_ / ROWS;  // 800 + 200
    k_gemm<<<nb_gemm, 256, 0, stream>>>(dec, enc, W_h, W_s, b_attn, WhT, Wsb);
    k_prelim<<<BT_, 512, 0, stream>>>(WhT, Wsb, v, mask, Acov);
    k_cumsum<<<(B_ * S_ + 63) / 64, 64, 0, stream>>>(Acov, out);
    k_final<<<BT_, 512, 0, stream>>>(WhT, Wsb, v, w_c, Acov, mask, enc, out);
}

// Round 9
// 163.299 us; speedup vs baseline: 1.1639x; 1.0032x over previous
//
#include <hip/hip_runtime.h>
#include <math.h>

#define B_ 8
#define T_ 100
#define S_ 400
#define H_ 256
#define BT_ (B_ * T_)
#define MAXL 30.0f
#define K_EXP 2.885390081777927f   // 2*log2(e): exp2(K*z) = e^(2z)

#define AF_OFF (BT_ * H_)
#define LOSS_OFF (BT_ * H_ + BT_ * S_)

// ws layout (floats)
#define WHT_OFF 0                        // WhT [B][H][S] (pre-scaled by K_EXP)
#define WSB_OFF (B_ * H_ * S_)           // Wsb [BT][H] = K*(dec@W_s + b_attn)
#define ACOV_OFF (WSB_OFF + BT_ * H_)    // A / cov [BT][S] (in-place scan)

__device__ __forceinline__ float wave_sum(float p) {
#pragma unroll
    for (int off = 32; off; off >>= 1) p += __shfl_xor(p, off, 64);
    return p;
}

__device__ __forceinline__ float wave_max(float p) {
#pragma unroll
    for (int off = 32; off; off >>= 1) p = fmaxf(p, __shfl_xor(p, off, 64));
    return p;
}

// ---------------- K1: WhT = K*(enc@W_h)^T, Wsb = K*(dec@W_s + b_attn) --------
#define ROWS 4
__global__ __launch_bounds__(256) void k_gemm(
    const float* __restrict__ dec, const float* __restrict__ enc,
    const float* __restrict__ W_h, const float* __restrict__ W_s,
    const float* __restrict__ b_attn,
    float* __restrict__ WhT, float* __restrict__ Wsb) {
    const int tid = threadIdx.x;          // output h
    const int blk = blockIdx.x;
    const int NB_ENC = (B_ * S_) / ROWS;  // 800

    float a0 = 0.f, a1 = 0.f, a2 = 0.f, a3 = 0.f;

    if (blk < NB_ENC) {
        const int r0 = blk * ROWS;            // 4 enc rows, same b
        const int b = r0 / S_, s0 = r0 - b * S_;
        const float* in = enc + (size_t)r0 * H_;   // block-uniform -> s_loads
        const float* Wp = W_h + tid;
#pragma unroll 8
        for (int h = 0; h < H_; ++h) {
            float w = Wp[(size_t)h * H_];
            a0 = fmaf(in[h], w, a0);
            a1 = fmaf(in[H_ + h], w, a1);
            a2 = fmaf(in[2 * H_ + h], w, a2);
            a3 = fmaf(in[3 * H_ + h], w, a3);
        }
        float* o = WhT + ((size_t)b * H_ + tid) * S_ + s0;
        o[0] = K_EXP * a0;
        o[1] = K_EXP * a1;
        o[2] = K_EXP * a2;
        o[3] = K_EXP * a3;
    } else {
        const int bt0 = (blk - NB_ENC) * ROWS;
        const float* in = dec + (size_t)bt0 * H_;
        const float* Wp = W_s + tid;
        const float bias = b_attn[tid];
#pragma unroll 8
        for (int h = 0; h < H_; ++h) {
            float w = Wp[(size_t)h * H_];
            a0 = fmaf(in[h], w, a0);
            a1 = fmaf(in[H_ + h], w, a1);
            a2 = fmaf(in[2 * H_ + h], w, a2);
            a3 = fmaf(in[3 * H_ + h], w, a3);
        }
        Wsb[(size_t)(bt0 + 0) * H_ + tid] = K_EXP * (a0 + bias);
        Wsb[(size_t)(bt0 + 1) * H_ + tid] = K_EXP * (a1 + bias);
        Wsb[(size_t)(bt0 + 2) * H_ + tid] = K_EXP * (a2 + bias);
        Wsb[(size_t)(bt0 + 3) * H_ + tid] = K_EXP * (a3 + bias);
    }
}

// ---------------- K2: prelim logits + softmax for a t-PAIR -------------------
// Block = (b, t-pair). One WhT load feeds both t's chains (2x ILP, 1/2 loads).
__global__ __launch_bounds__(512) void k_prelim(
    const float* __restrict__ WhT, const float* __restrict__ Wsb,
    const float* __restrict__ v,
    const unsigned char* __restrict__ mask,
    float* __restrict__ A) {
    __shared__ float red[32];
    const int blk = blockIdx.x;
    const int b = blk & 7;
    const int tp = blk >> 3;
    const int bt0 = b * T_ + 2 * tp;
    const int tid = threadIdx.x;
    const int lane = tid & 63;
    const int wid = tid >> 6;   // 0..7
    const int s = tid;
    const bool act = (s < S_);

    const float4 vv4 = *reinterpret_cast<const float4*>(v + 4 * lane);
    const float sumv = wave_sum((vv4.x + vv4.y) + (vv4.z + vv4.w));

    const float* Ws0 = Wsb + (size_t)bt0 * H_;   // uniform -> s_loads
    const float* Ws1 = Ws0 + H_;
    float acc0 = 0.f, acc1 = 0.f;
    if (act) {
        const float* wcol = WhT + (size_t)b * H_ * S_ + s;
#pragma unroll 8
        for (int h = 0; h < H_; ++h) {
            float w = wcol[(size_t)h * S_];
            float vh = v[h];
            float r0 = __builtin_amdgcn_rcpf(__builtin_amdgcn_exp2f(w + Ws0[h]) + 1.0f);
            float r1 = __builtin_amdgcn_rcpf(__builtin_amdgcn_exp2f(w + Ws1[h]) + 1.0f);
            acc0 = fmaf(r0, vh, acc0);
            acc1 = fmaf(r1, vh, acc1);
        }
    }

    float e0 = -INFINITY, e1 = -INFINITY;
    if (act) {
        e0 = fminf(fmaxf(sumv - 2.f * acc0, -MAXL), MAXL);
        e1 = fminf(fmaxf(sumv - 2.f * acc1, -MAXL), MAXL);
        if (mask[(size_t)b * S_ + s]) { e0 = -INFINITY; e1 = -INFINITY; }
    }

    float mx0 = wave_max(e0);
    float mx1 = wave_max(e1);
    if (lane == 0) { red[wid] = mx0; red[8 + wid] = mx1; }
    __syncthreads();
    mx0 = fmaxf(fmaxf(fmaxf(red[0], red[1]), fmaxf(red[2], red[3])),
                fmaxf(fmaxf(red[4], red[5]), fmaxf(red[6], red[7])));
    mx1 = fmaxf(fmaxf(fmaxf(red[8], red[9]), fmaxf(red[10], red[11])),
                fmaxf(fmaxf(red[12], red[13]), fmaxf(red[14], red[15])));

    float p0 = act ? __expf(e0 - mx0) : 0.f;
    float p1 = act ? __expf(e1 - mx1) : 0.f;
    float sm0 = wave_sum(p0);
    float sm1 = wave_sum(p1);
    if (lane == 0) { red[16 + wid] = sm0; red[24 + wid] = sm1; }
    __syncthreads();
    sm0 = ((red[16] + red[17]) + (red[18] + red[19])) +
          ((red[20] + red[21]) + (red[22] + red[23]));
    sm1 = ((red[24] + red[25]) + (red[26] + red[27])) +
          ((red[28] + red[29]) + (red[30] + red[31]));

    if (act) {
        A[(size_t)bt0 * S_ + s] = p0 * __builtin_amdgcn_rcpf(sm0);
        A[(size_t)(bt0 + 1) * S_ + s] = p1 * __builtin_amdgcn_rcpf(sm1);
    }
}

// ---------------- K3: in-place exclusive scan over t; zero loss --------------
__global__ __launch_bounds__(64) void k_cumsum(float* __restrict__ A,
                                               float* __restrict__ out) {
    const int idx = blockIdx.x * 64 + threadIdx.x;  // b*S + s
    if (idx == 0) out[LOSS_OFF] = 0.f;
    if (idx >= B_ * S_) return;
    const int b = idx / S_;
    const int s = idx - b * S_;
    float* col = A + (size_t)b * T_ * S_ + s;
    float run = 0.f;
#pragma unroll 10
    for (int t = 0; t < T_; ++t) {
        float a = col[(size_t)t * S_];
        col[(size_t)t * S_] = run;  // cov_shifted
        run += a;
    }
}

// ---------------- K4: final logits + softmax + context + loss (t-pair) -------
__global__ __launch_bounds__(512) void k_final(
    const float* __restrict__ WhT, const float* __restrict__ Wsb,
    const float* __restrict__ v, const float* __restrict__ w_c,
    const float* __restrict__ cov,
    const unsigned char* __restrict__ mask,
    const float* __restrict__ enc,
    float* __restrict__ out) {
    __shared__ float e0_lds[S_], e1_lds[S_];
    __shared__ float ctx0[H_], ctx1[H_];
    __shared__ float red[32];
    const int blk = blockIdx.x;
    const int b = blk & 7;
    const int tp = blk >> 3;
    const int bt0 = b * T_ + 2 * tp;
    const int tid = threadIdx.x;
    const int lane = tid & 63;
    const int wid = tid >> 6;
    const int s = tid;
    const bool act = (s < S_);

    const float4 vv4 = *reinterpret_cast<const float4*>(v + 4 * lane);
    const float sumv = wave_sum((vv4.x + vv4.y) + (vv4.z + vv4.w));

    float c0 = 0.f, c1 = 0.f;
    if (act) {
        c0 = cov[(size_t)bt0 * S_ + s];
        c1 = cov[(size_t)(bt0 + 1) * S_ + s];
    }
    const float ck0 = K_EXP * c0, ck1 = K_EXP * c1;

    const float* Ws0 = Wsb + (size_t)bt0 * H_;
    const float* Ws1 = Ws0 + H_;
    float acc0 = 0.f, acc1 = 0.f;
    if (act) {
        const float* wcol = WhT + (size_t)b * H_ * S_ + s;
#pragma unroll 8
        for (int h = 0; h < H_; ++h) {
            float w = wcol[(size_t)h * S_];
            float wch = w_c[h];
            float vh = v[h];
            float a0 = fmaf(ck0, wch, w + Ws0[h]);
            float a1 = fmaf(ck1, wch, w + Ws1[h]);
            float r0 = __builtin_amdgcn_rcpf(__builtin_amdgcn_exp2f(a0) + 1.0f);
            float r1 = __builtin_amdgcn_rcpf(__builtin_amdgcn_exp2f(a1) + 1.0f);
            acc0 = fmaf(r0, vh, acc0);
            acc1 = fmaf(r1, vh, acc1);
        }
    }

    float e0 = -INFINITY, e1 = -INFINITY;
    if (act) {
        e0 = fminf(fmaxf(sumv - 2.f * acc0, -MAXL), MAXL);
        e1 = fminf(fmaxf(sumv - 2.f * acc1, -MAXL), MAXL);
        if (mask[(size_t)b * S_ + s]) { e0 = -INFINITY; e1 = -INFINITY; }
    }

    float mx0 = wave_max(e0);
    float mx1 = wave_max(e1);
    if (lane == 0) { red[wid] = mx0; red[8 + wid] = mx1; }
    __syncthreads();
    mx0 = fmaxf(fmaxf(fmaxf(red[0], red[1]), fmaxf(red[2], red[3])),
                fmaxf(fmaxf(red[4], red[5]), fmaxf(red[6], red[7])));
    mx1 = fmaxf(fmaxf(fmaxf(red[8], red[9]), fmaxf(red[10], red[11])),
                fmaxf(fmaxf(red[12], red[13]), fmaxf(red[14], red[15])));

    float p0 = act ? __expf(e0 - mx0) : 0.f;
    float p1 = act ? __expf(e1 - mx1) : 0.f;
    float sm0 = wave_sum(p0);
    float sm1 = wave_sum(p1);
    if (lane == 0) { red[16 + wid] = sm0; red[24 + wid] = sm1; }
    __syncthreads();
    sm0 = ((red[16] + red[17]) + (red[18] + red[19])) +
          ((red[20] + red[21]) + (red[22] + red[23]));
    sm1 = ((red[24] + red[25]) + (red[26] + red[27])) +
          ((red[28] + red[29]) + (red[30] + red[31]));

    const float a0 = act ? p0 * __builtin_amdgcn_rcpf(sm0) : 0.f;
    const float a1 = act ? p1 * __builtin_amdgcn_rcpf(sm1) : 0.f;

    // coverage-loss partials for both t (registers only)
    float lp = act ? (fminf(a0, c0) + fminf(a1, c1)) : 0.f;
    lp = wave_sum(lp);
    if (lane == 0) red[wid] = lp;

    if (act) {
        e0_lds[s] = a0;
        e1_lds[s] = a1;
        out[AF_OFF + (size_t)bt0 * S_ + s] = a0;
        out[AF_OFF + (size_t)(bt0 + 1) * S_ + s] = a1;
    }
    __syncthreads();

    if (tid == 0) {
        float tot = ((red[0] + red[1]) + (red[2] + red[3])) +
                    ((red[4] + red[5]) + (red[6] + red[7]));
        atomicAdd(out + LOSS_OFF, tot * (1.0f / (B_ * T_)));
    }

    // context for both t: one enc stream feeds both accumulator sets.
    const int h = tid & (H_ - 1);
    const int half = tid >> 8;           // 0 or 1
    const int sb = half * (S_ / 2);      // 0 or 200
    const float* eb = enc + ((size_t)b * S_ + sb) * H_ + h;
    float q00 = 0.f, q01 = 0.f, q02 = 0.f, q03 = 0.f;
    float q10 = 0.f, q11 = 0.f, q12 = 0.f, q13 = 0.f;
#pragma unroll 5
    for (int j = 0; j < S_ / 2; j += 4) {
        float w0 = eb[(size_t)j * H_];
        float w1 = eb[(size_t)(j + 1) * H_];
        float w2 = eb[(size_t)(j + 2) * H_];
        float w3 = eb[(size_t)(j + 3) * H_];
        q00 = fmaf(e0_lds[sb + j], w0, q00);
        q10 = fmaf(e1_lds[sb + j], w0, q10);
        q01 = fmaf(e0_lds[sb + j + 1], w1, q01);
        q11 = fmaf(e1_lds[sb + j + 1], w1, q11);
        q02 = fmaf(e0_lds[sb + j + 2], w2, q02);
        q12 = fmaf(e1_lds[sb + j + 2], w2, q12);
        q03 = fmaf(e0_lds[sb + j + 3], w3, q03);
        q13 = fmaf(e1_lds[sb + j + 3], w3, q13);
    }
    const float r0 = (q00 + q01) + (q02 + q03);
    const float r1 = (q10 + q11) + (q12 + q13);
    if (half == 0) { ctx0[h] = r0; ctx1[h] = r1; }
    __syncthreads();
    if (half == 1) {
        out[(size_t)bt0 * H_ + h] = ctx0[h] + r0;
        out[(size_t)(bt0 + 1) * H_ + h] = ctx1[h] + r1;
    }
}

extern "C" void kernel_launch(void* const* d_in, const int* in_sizes, int n_in,
                              void* d_out, int out_size, void* d_ws, size_t ws_size,
                              hipStream_t stream) {
    const float* dec = (const float*)d_in[0];
    const float* enc = (const float*)d_in[1];
    const unsigned char* mask = (const unsigned char*)d_in[2];
    const float* W_h = (const float*)d_in[3];
    const float* W_s = (const float*)d_in[4];
    const float* w_c = (const float*)d_in[5];
    const float* v = (const float*)d_in[6];
    const float* b_attn = (const float*)d_in[7];

    float* out = (float*)d_out;
    float* ws = (float*)d_ws;
    float* WhT = ws + WHT_OFF;
    float* Wsb = ws + WSB_OFF;
    float* Acov = ws + ACOV_OFF;

    const int nb_gemm = (B_ * S_) / ROWS + BT_ / ROWS;  // 800 + 200
    const int nb_pair = B_ * (T_ / 2);                  // 400
    k_gemm<<<nb_gemm, 256, 0, stream>>>(dec, enc, W_h, W_s, b_attn, WhT, Wsb);
    k_prelim<<<nb_pair, 512, 0, stream>>>(WhT, Wsb, v, mask, Acov);
    k_cumsum<<<(B_ * S_ + 63) / 64, 64, 0, stream>>>(Acov, out);
    k_final<<<nb_pair, 512, 0, stream>>>(WhT, Wsb, v, w_c, Acov, mask, enc, out);
}

// Round 10
// 162.178 us; speedup vs baseline: 1.1719x; 1.0069x over previous
//
#include <hip/hip_runtime.h>
#include <math.h>

#define B_ 8
#define T_ 100
#define S_ 400
#define H_ 256
#define BT_ (B_ * T_)
#define MAXL 30.0f
#define K_EXP 2.885390081777927f   // 2*log2(e): exp2(K*z) = e^(2z)

#define AF_OFF (BT_ * H_)
#define LOSS_OFF (BT_ * H_ + BT_ * S_)

// ws layout (floats) — all exp-domain
#define EWHT_OFF 0                        // EWhT [B][H][S] = exp2(K*Wh)
#define EWSB_OFF (B_ * H_ * S_)           // EWsb [BT][H] = exp2(K*(Ws+b))
#define ACOV_OFF (EWSB_OFF + BT_ * H_)    // A / cov [BT][S] (in-place scan)

__device__ __forceinline__ float wave_sum(float p) {
#pragma unroll
    for (int off = 32; off; off >>= 1) p += __shfl_xor(p, off, 64);
    return p;
}

__device__ __forceinline__ float wave_max(float p) {
#pragma unroll
    for (int off = 32; off; off >>= 1) p = fmaxf(p, __shfl_xor(p, off, 64));
    return p;
}

// ---------------- K1: EWhT = exp2(K*enc@W_h)^T, EWsb = exp2(K*(dec@W_s+b)) ---
#define ROWS 8
__global__ __launch_bounds__(256) void k_gemm(
    const float* __restrict__ dec, const float* __restrict__ enc,
    const float* __restrict__ W_h, const float* __restrict__ W_s,
    const float* __restrict__ b_attn,
    float* __restrict__ EWhT, float* __restrict__ EWsb) {
    const int tid = threadIdx.x;          // output h
    const int blk = blockIdx.x;
    const int NB_ENC = (B_ * S_) / ROWS;  // 400

    float acc[ROWS];
#pragma unroll
    for (int r = 0; r < ROWS; ++r) acc[r] = 0.f;

    if (blk < NB_ENC) {
        const int r0 = blk * ROWS;            // 8 enc rows, same b
        const int b = r0 / S_, s0 = r0 - b * S_;
        const float* in = enc + (size_t)r0 * H_;   // block-uniform -> s_loads
        const float* Wp = W_h + tid;
#pragma unroll 4
        for (int h = 0; h < H_; ++h) {
            float w = Wp[(size_t)h * H_];
#pragma unroll
            for (int r = 0; r < ROWS; ++r)
                acc[r] = fmaf(in[r * H_ + h], w, acc[r]);
        }
        float* o = EWhT + ((size_t)b * H_ + tid) * S_ + s0;
#pragma unroll
        for (int r = 0; r < ROWS; ++r)
            o[r] = __builtin_amdgcn_exp2f(K_EXP * acc[r]);
    } else {
        const int bt0 = (blk - NB_ENC) * ROWS;
        const float* in = dec + (size_t)bt0 * H_;
        const float* Wp = W_s + tid;
        const float bias = b_attn[tid];
#pragma unroll 4
        for (int h = 0; h < H_; ++h) {
            float w = Wp[(size_t)h * H_];
#pragma unroll
            for (int r = 0; r < ROWS; ++r)
                acc[r] = fmaf(in[r * H_ + h], w, acc[r]);
        }
#pragma unroll
        for (int r = 0; r < ROWS; ++r)
            EWsb[(size_t)(bt0 + r) * H_ + tid] =
                __builtin_amdgcn_exp2f(K_EXP * (acc[r] + bias));
    }
}

// ---------------- K2: prelim logits + softmax (t-pair, 1 trans/elem) ---------
__global__ __launch_bounds__(512) void k_prelim(
    const float* __restrict__ EWhT, const float* __restrict__ EWsb,
    const float* __restrict__ v,
    const unsigned char* __restrict__ mask,
    float* __restrict__ A) {
    __shared__ float red[32];
    const int blk = blockIdx.x;
    const int b = blk & 7;
    const int tp = blk >> 3;
    const int bt0 = b * T_ + 2 * tp;
    const int tid = threadIdx.x;
    const int lane = tid & 63;
    const int wid = tid >> 6;   // 0..7
    const int s = tid;
    const bool act = (s < S_);

    const float4 vv4 = *reinterpret_cast<const float4*>(v + 4 * lane);
    const float sumv = wave_sum((vv4.x + vv4.y) + (vv4.z + vv4.w));

    const float* E0 = EWsb + (size_t)bt0 * H_;   // uniform -> s_loads
    const float* E1 = E0 + H_;
    float acc0 = 0.f, acc1 = 0.f;
    if (act) {
        const float* ecol = EWhT + (size_t)b * H_ * S_ + s;
#pragma unroll 8
        for (int h = 0; h < H_; ++h) {
            float Ew = ecol[(size_t)h * S_];
            float vh = v[h];
            float r0 = __builtin_amdgcn_rcpf(fmaf(Ew, E0[h], 1.0f));
            float r1 = __builtin_amdgcn_rcpf(fmaf(Ew, E1[h], 1.0f));
            acc0 = fmaf(r0, vh, acc0);
            acc1 = fmaf(r1, vh, acc1);
        }
    }

    float e0 = -INFINITY, e1 = -INFINITY;
    if (act) {
        e0 = fminf(fmaxf(sumv - 2.f * acc0, -MAXL), MAXL);
        e1 = fminf(fmaxf(sumv - 2.f * acc1, -MAXL), MAXL);
        if (mask[(size_t)b * S_ + s]) { e0 = -INFINITY; e1 = -INFINITY; }
    }

    float mx0 = wave_max(e0);
    float mx1 = wave_max(e1);
    if (lane == 0) { red[wid] = mx0; red[8 + wid] = mx1; }
    __syncthreads();
    mx0 = fmaxf(fmaxf(fmaxf(red[0], red[1]), fmaxf(red[2], red[3])),
                fmaxf(fmaxf(red[4], red[5]), fmaxf(red[6], red[7])));
    mx1 = fmaxf(fmaxf(fmaxf(red[8], red[9]), fmaxf(red[10], red[11])),
                fmaxf(fmaxf(red[12], red[13]), fmaxf(red[14], red[15])));

    float p0 = act ? __expf(e0 - mx0) : 0.f;
    float p1 = act ? __expf(e1 - mx1) : 0.f;
    float sm0 = wave_sum(p0);
    float sm1 = wave_sum(p1);
    if (lane == 0) { red[16 + wid] = sm0; red[24 + wid] = sm1; }
    __syncthreads();
    sm0 = ((red[16] + red[17]) + (red[18] + red[19])) +
          ((red[20] + red[21]) + (red[22] + red[23]));
    sm1 = ((red[24] + red[25]) + (red[26] + red[27])) +
          ((red[28] + red[29]) + (red[30] + red[31]));

    if (act) {
        A[(size_t)bt0 * S_ + s] = p0 * __builtin_amdgcn_rcpf(sm0);
        A[(size_t)(bt0 + 1) * S_ + s] = p1 * __builtin_amdgcn_rcpf(sm1);
    }
}

// ---------------- K3: in-place exclusive scan over t; zero loss --------------
__global__ __launch_bounds__(64) void k_cumsum(float* __restrict__ A,
                                               float* __restrict__ out) {
    const int idx = blockIdx.x * 64 + threadIdx.x;  // b*S + s
    if (idx == 0) out[LOSS_OFF] = 0.f;
    if (idx >= B_ * S_) return;
    const int b = idx / S_;
    const int s = idx - b * S_;
    float* col = A + (size_t)b * T_ * S_ + s;
    float run = 0.f;
#pragma unroll 10
    for (int t = 0; t < T_; ++t) {
        float a = col[(size_t)t * S_];
        col[(size_t)t * S_] = run;  // cov_shifted
        run += a;
    }
}

// ---------------- K4: final logits + softmax + context + loss (t-pair) -------
__global__ __launch_bounds__(512) void k_final(
    const float* __restrict__ EWhT, const float* __restrict__ EWsb,
    const float* __restrict__ v, const float* __restrict__ w_c,
    const float* __restrict__ cov,
    const unsigned char* __restrict__ mask,
    const float* __restrict__ enc,
    float* __restrict__ out) {
    __shared__ float e0_lds[S_], e1_lds[S_];
    __shared__ float ctx0[H_], ctx1[H_];
    __shared__ float red[32];
    const int blk = blockIdx.x;
    const int b = blk & 7;
    const int tp = blk >> 3;
    const int bt0 = b * T_ + 2 * tp;
    const int tid = threadIdx.x;
    const int lane = tid & 63;
    const int wid = tid >> 6;
    const int s = tid;
    const bool act = (s < S_);

    const float4 vv4 = *reinterpret_cast<const float4*>(v + 4 * lane);
    const float sumv = wave_sum((vv4.x + vv4.y) + (vv4.z + vv4.w));

    float c0 = 0.f, c1 = 0.f;
    if (act) {
        c0 = cov[(size_t)bt0 * S_ + s];
        c1 = cov[(size_t)(bt0 + 1) * S_ + s];
    }
    const float ck0 = K_EXP * c0, ck1 = K_EXP * c1;

    const float* E0 = EWsb + (size_t)bt0 * H_;
    const float* E1 = E0 + H_;
    float acc0 = 0.f, acc1 = 0.f;
    if (act) {
        const float* ecol = EWhT + (size_t)b * H_ * S_ + s;
#pragma unroll 8
        for (int h = 0; h < H_; ++h) {
            float Ew = ecol[(size_t)h * S_];
            float wch = w_c[h];
            float vh = v[h];
            float Ec0 = __builtin_amdgcn_exp2f(ck0 * wch);
            float Ec1 = __builtin_amdgcn_exp2f(ck1 * wch);
            float r0 = __builtin_amdgcn_rcpf(fmaf(Ew * E0[h], Ec0, 1.0f));
            float r1 = __builtin_amdgcn_rcpf(fmaf(Ew * E1[h], Ec1, 1.0f));
            acc0 = fmaf(r0, vh, acc0);
            acc1 = fmaf(r1, vh, acc1);
        }
    }

    float e0 = -INFINITY, e1 = -INFINITY;
    if (act) {
        e0 = fminf(fmaxf(sumv - 2.f * acc0, -MAXL), MAXL);
        e1 = fminf(fmaxf(sumv - 2.f * acc1, -MAXL), MAXL);
        if (mask[(size_t)b * S_ + s]) { e0 = -INFINITY; e1 = -INFINITY; }
    }

    float mx0 = wave_max(e0);
    float mx1 = wave_max(e1);
    if (lane == 0) { red[wid] = mx0; red[8 + wid] = mx1; }
    __syncthreads();
    mx0 = fmaxf(fmaxf(fmaxf(red[0], red[1]), fmaxf(red[2], red[3])),
                fmaxf(fmaxf(red[4], red[5]), fmaxf(red[6], red[7])));
    mx1 = fmaxf(fmaxf(fmaxf(red[8], red[9]), fmaxf(red[10], red[11])),
                fmaxf(fmaxf(red[12], red[13]), fmaxf(red[14], red[15])));

    float p0 = act ? __expf(e0 - mx0) : 0.f;
    float p1 = act ? __expf(e1 - mx1) : 0.f;
    float sm0 = wave_sum(p0);
    float sm1 = wave_sum(p1);
    if (lane == 0) { red[16 + wid] = sm0; red[24 + wid] = sm1; }
    __syncthreads();
    sm0 = ((red[16] + red[17]) + (red[18] + red[19])) +
          ((red[20] + red[21]) + (red[22] + red[23]));
    sm1 = ((red[24] + red[25]) + (red[26] + red[27])) +
          ((red[28] + red[29]) + (red[30] + red[31]));

    const float a0 = act ? p0 * __builtin_amdgcn_rcpf(sm0) : 0.f;
    const float a1 = act ? p1 * __builtin_amdgcn_rcpf(sm1) : 0.f;

    // coverage-loss partials for both t (registers only)
    float lp = act ? (fminf(a0, c0) + fminf(a1, c1)) : 0.f;
    lp = wave_sum(lp);
    if (lane == 0) red[wid] = lp;

    if (act) {
        e0_lds[s] = a0;
        e1_lds[s] = a1;
        out[AF_OFF + (size_t)bt0 * S_ + s] = a0;
        out[AF_OFF + (size_t)(bt0 + 1) * S_ + s] = a1;
    }
    __syncthreads();

    if (tid == 0) {
        float tot = ((red[0] + red[1]) + (red[2] + red[3])) +
                    ((red[4] + red[5]) + (red[6] + red[7]));
        atomicAdd(out + LOSS_OFF, tot * (1.0f / (B_ * T_)));
    }

    // context for both t: one enc stream feeds both accumulator sets.
    const int h = tid & (H_ - 1);
    const int half = tid >> 8;           // 0 or 1
    const int sb = half * (S_ / 2);      // 0 or 200
    const float* eb = enc + ((size_t)b * S_ + sb) * H_ + h;
    float q00 = 0.f, q01 = 0.f, q02 = 0.f, q03 = 0.f;
    float q10 = 0.f, q11 = 0.f, q12 = 0.f, q13 = 0.f;
#pragma unroll 5
    for (int j = 0; j < S_ / 2; j += 4) {
        float w0 = eb[(size_t)j * H_];
        float w1 = eb[(size_t)(j + 1) * H_];
        float w2 = eb[(size_t)(j + 2) * H_];
        float w3 = eb[(size_t)(j + 3) * H_];
        q00 = fmaf(e0_lds[sb + j], w0, q00);
        q10 = fmaf(e1_lds[sb + j], w0, q10);
        q01 = fmaf(e0_lds[sb + j + 1], w1, q01);
        q11 = fmaf(e1_lds[sb + j + 1], w1, q11);
        q02 = fmaf(e0_lds[sb + j + 2], w2, q02);
        q12 = fmaf(e1_lds[sb + j + 2], w2, q12);
        q03 = fmaf(e0_lds[sb + j + 3], w3, q03);
        q13 = fmaf(e1_lds[sb + j + 3], w3, q13);
    }
    const float r0 = (q00 + q01) + (q02 + q03);
    const float r1 = (q10 + q11) + (q12 + q13);
    if (half == 0) { ctx0[h] = r0; ctx1[h] = r1; }
    __syncthreads();
    if (half == 1) {
        out[(size_t)bt0 * H_ + h] = ctx0[h] + r0;
        out[(size_t)(bt0 + 1) * H_ + h] = ctx1[h] + r1;
    }
}

extern "C" void kernel_launch(void* const* d_in, const int* in_sizes, int n_in,
                              void* d_out, int out_size, void* d_ws, size_t ws_size,
                              hipStream_t stream) {
    const float* dec = (const float*)d_in[0];
    const float* enc = (const float*)d_in[1];
    const unsigned char* mask = (const unsigned char*)d_in[2];
    const float* W_h = (const float*)d_in[3];
    const float* W_s = (const float*)d_in[4];
    const float* w_c = (const float*)d_in[5];
    const float* v = (const float*)d_in[6];
    const float* b_attn = (const float*)d_in[7];

    float* out = (float*)d_out;
    float* ws = (float*)d_ws;
    float* EWhT = ws + EWHT_OFF;
    float* EWsb = ws + EWSB_OFF;
    float* Acov = ws + ACOV_OFF;

    const int nb_gemm = (B_ * S_) / ROWS + BT_ / ROWS;  // 400 + 100
    const int nb_pair = B_ * (T_ / 2);                  // 400
    k_gemm<<<nb_gemm, 256, 0, stream>>>(dec, enc, W_h, W_s, b_attn, EWhT, EWsb);
    k_prelim<<<nb_pair, 512, 0, stream>>>(EWhT, EWsb, v, mask, Acov);
    k_cumsum<<<(B_ * S_ + 63) / 64, 64, 0, stream>>>(Acov, out);
    k_final<<<nb_pair, 512, 0, stream>>>(EWhT, EWsb, v, w_c, Acov, mask, enc, out);
}

// Round 11
// 155.409 us; speedup vs baseline: 1.2230x; 1.0436x over previous
//
#include <hip/hip_runtime.h>
#include <math.h>

#define B_ 8
#define T_ 100
#define S_ 400
#define H_ 256
#define HQ_ (H_ / 4)
#define BT_ (B_ * T_)
#define MAXL 30.0f
#define K_EXP 2.885390081777927f   // 2*log2(e): exp2(K*z) = e^(2z)

#define AF_OFF (BT_ * H_)
#define LOSS_OFF (BT_ * H_ + BT_ * S_)

// ws layout (floats) — exp-domain
#define EWHT_OFF 0                        // EWhT4 [B][H/4][S][4] = exp2(K*Wh)
#define EWSB_OFF (B_ * H_ * S_)           // EWsb [BT][H] = exp2(K*(Ws+b))
#define ACOV_OFF (EWSB_OFF + BT_ * H_)    // A / cov [BT][S] (in-place scan)

__device__ __forceinline__ float wave_sum(float p) {
#pragma unroll
    for (int off = 32; off; off >>= 1) p += __shfl_xor(p, off, 64);
    return p;
}

__device__ __forceinline__ float wave_max(float p) {
#pragma unroll
    for (int off = 32; off; off >>= 1) p = fmaxf(p, __shfl_xor(p, off, 64));
    return p;
}

// ---------------- K1: EWhT4 (quad-interleaved), EWsb -------------------------
#define ROWS 8
__global__ __launch_bounds__(256) void k_gemm(
    const float* __restrict__ dec, const float* __restrict__ enc,
    const float* __restrict__ W_h, const float* __restrict__ W_s,
    const float* __restrict__ b_attn,
    float* __restrict__ EWhT4, float* __restrict__ EWsb) {
    const int tid = threadIdx.x;          // output h
    const int blk = blockIdx.x;
    const int NB_ENC = (B_ * S_) / ROWS;  // 400

    float acc[ROWS];
#pragma unroll
    for (int r = 0; r < ROWS; ++r) acc[r] = 0.f;

    if (blk < NB_ENC) {
        const int r0 = blk * ROWS;            // 8 enc rows, same b
        const int b = r0 / S_, s0 = r0 - b * S_;
        const float* in = enc + (size_t)r0 * H_;   // block-uniform -> s_loads
        const float* Wp = W_h + tid;
#pragma unroll 4
        for (int h = 0; h < H_; ++h) {
            float w = Wp[(size_t)h * H_];
#pragma unroll
            for (int r = 0; r < ROWS; ++r)
                acc[r] = fmaf(in[r * H_ + h], w, acc[r]);
        }
        // quad-interleaved store: ((b*HQ + h/4)*S + s)*4 + (h&3)
        float* o = EWhT4 + (((size_t)b * HQ_ + (tid >> 2)) * S_ + s0) * 4 + (tid & 3);
#pragma unroll
        for (int r = 0; r < ROWS; ++r)
            o[r * 4] = __builtin_amdgcn_exp2f(K_EXP * acc[r]);
    } else {
        const int bt0 = (blk - NB_ENC) * ROWS;
        const float* in = dec + (size_t)bt0 * H_;
        const float* Wp = W_s + tid;
        const float bias = b_attn[tid];
#pragma unroll 4
        for (int h = 0; h < H_; ++h) {
            float w = Wp[(size_t)h * H_];
#pragma unroll
            for (int r = 0; r < ROWS; ++r)
                acc[r] = fmaf(in[r * H_ + h], w, acc[r]);
        }
#pragma unroll
        for (int r = 0; r < ROWS; ++r)
            EWsb[(size_t)(bt0 + r) * H_ + tid] =
                __builtin_amdgcn_exp2f(K_EXP * (acc[r] + bias));
    }
}

// ---------------- K2: prelim logits + softmax (t-pair, 4-way rcp) ------------
// sum_i v_i/(1+Q_i) over an h-quad = num/den with ONE rcp per 4 elements.
__global__ __launch_bounds__(512) void k_prelim(
    const float* __restrict__ EWhT4, const float* __restrict__ EWsb,
    const float* __restrict__ v,
    const unsigned char* __restrict__ mask,
    float* __restrict__ A) {
    __shared__ float red[32];
    const int blk = blockIdx.x;
    const int b = blk & 7;
    const int tp = blk >> 3;
    const int bt0 = b * T_ + 2 * tp;
    const int tid = threadIdx.x;
    const int lane = tid & 63;
    const int wid = tid >> 6;   // 0..7
    const int s = tid;
    const bool act = (s < S_);

    const float4 vv4 = *reinterpret_cast<const float4*>(v + 4 * lane);
    const float sumv = wave_sum((vv4.x + vv4.y) + (vv4.z + vv4.w));

    const float* E0 = EWsb + (size_t)bt0 * H_;   // uniform -> s_loads
    const float* E1 = E0 + H_;
    float acc0 = 0.f, acc1 = 0.f;
    if (act) {
        const float4* eq = reinterpret_cast<const float4*>(
                               EWhT4 + (size_t)b * HQ_ * S_ * 4) + s;
#pragma unroll 4
        for (int hq = 0; hq < HQ_; ++hq) {
            const float4 Ew = eq[(size_t)hq * S_];
            const int h = 4 * hq;
            const float v0 = v[h], v1 = v[h + 1], v2 = v[h + 2], v3 = v[h + 3];
            // t0
            {
                float p0 = fmaf(Ew.x, E0[h], 1.f);
                float p1 = fmaf(Ew.y, E0[h + 1], 1.f);
                float p2 = fmaf(Ew.z, E0[h + 2], 1.f);
                float p3 = fmaf(Ew.w, E0[h + 3], 1.f);
                float p01 = p0 * p1, p23 = p2 * p3;
                float num = fmaf(fmaf(v0, p1, v1 * p0), p23,
                                 fmaf(v2, p3, v3 * p2) * p01);
                acc0 = fmaf(num, __builtin_amdgcn_rcpf(p01 * p23), acc0);
            }
            // t1
            {
                float p0 = fmaf(Ew.x, E1[h], 1.f);
                float p1 = fmaf(Ew.y, E1[h + 1], 1.f);
                float p2 = fmaf(Ew.z, E1[h + 2], 1.f);
                float p3 = fmaf(Ew.w, E1[h + 3], 1.f);
                float p01 = p0 * p1, p23 = p2 * p3;
                float num = fmaf(fmaf(v0, p1, v1 * p0), p23,
                                 fmaf(v2, p3, v3 * p2) * p01);
                acc1 = fmaf(num, __builtin_amdgcn_rcpf(p01 * p23), acc1);
            }
        }
    }

    float e0 = -INFINITY, e1 = -INFINITY;
    if (act) {
        e0 = fminf(fmaxf(sumv - 2.f * acc0, -MAXL), MAXL);
        e1 = fminf(fmaxf(sumv - 2.f * acc1, -MAXL), MAXL);
        if (mask[(size_t)b * S_ + s]) { e0 = -INFINITY; e1 = -INFINITY; }
    }

    float mx0 = wave_max(e0);
    float mx1 = wave_max(e1);
    if (lane == 0) { red[wid] = mx0; red[8 + wid] = mx1; }
    __syncthreads();
    mx0 = fmaxf(fmaxf(fmaxf(red[0], red[1]), fmaxf(red[2], red[3])),
                fmaxf(fmaxf(red[4], red[5]), fmaxf(red[6], red[7])));
    mx1 = fmaxf(fmaxf(fmaxf(red[8], red[9]), fmaxf(red[10], red[11])),
                fmaxf(fmaxf(red[12], red[13]), fmaxf(red[14], red[15])));

    float p0 = act ? __expf(e0 - mx0) : 0.f;
    float p1 = act ? __expf(e1 - mx1) : 0.f;
    float sm0 = wave_sum(p0);
    float sm1 = wave_sum(p1);
    if (lane == 0) { red[16 + wid] = sm0; red[24 + wid] = sm1; }
    __syncthreads();
    sm0 = ((red[16] + red[17]) + (red[18] + red[19])) +
          ((red[20] + red[21]) + (red[22] + red[23]));
    sm1 = ((red[24] + red[25]) + (red[26] + red[27])) +
          ((red[28] + red[29]) + (red[30] + red[31]));

    if (act) {
        A[(size_t)bt0 * S_ + s] = p0 * __builtin_amdgcn_rcpf(sm0);
        A[(size_t)(bt0 + 1) * S_ + s] = p1 * __builtin_amdgcn_rcpf(sm1);
    }
}

// ---------------- K3: in-place exclusive scan over t; zero loss --------------
__global__ __launch_bounds__(64) void k_cumsum(float* __restrict__ A,
                                               float* __restrict__ out) {
    const int idx = blockIdx.x * 64 + threadIdx.x;  // b*S + s
    if (idx == 0) out[LOSS_OFF] = 0.f;
    if (idx >= B_ * S_) return;
    const int b = idx / S_;
    const int s = idx - b * S_;
    float* col = A + (size_t)b * T_ * S_ + s;
    float run = 0.f;
#pragma unroll 10
    for (int t = 0; t < T_; ++t) {
        float a = col[(size_t)t * S_];
        col[(size_t)t * S_] = run;  // cov_shifted
        run += a;
    }
}

// ---------------- K4: final logits + softmax + context + loss (t-pair) -------
__global__ __launch_bounds__(512) void k_final(
    const float* __restrict__ EWhT4, const float* __restrict__ EWsb,
    const float* __restrict__ v, const float* __restrict__ w_c,
    const float* __restrict__ cov,
    const unsigned char* __restrict__ mask,
    const float* __restrict__ enc,
    float* __restrict__ out) {
    __shared__ float e0_lds[S_], e1_lds[S_];
    __shared__ float ctx0[H_], ctx1[H_];
    __shared__ float red[32];
    const int blk = blockIdx.x;
    const int b = blk & 7;
    const int tp = blk >> 3;
    const int bt0 = b * T_ + 2 * tp;
    const int tid = threadIdx.x;
    const int lane = tid & 63;
    const int wid = tid >> 6;
    const int s = tid;
    const bool act = (s < S_);

    const float4 vv4 = *reinterpret_cast<const float4*>(v + 4 * lane);
    const float sumv = wave_sum((vv4.x + vv4.y) + (vv4.z + vv4.w));

    float c0 = 0.f, c1 = 0.f;
    if (act) {
        c0 = cov[(size_t)bt0 * S_ + s];
        c1 = cov[(size_t)(bt0 + 1) * S_ + s];
    }
    const float ck0 = K_EXP * c0, ck1 = K_EXP * c1;

    const float* E0 = EWsb + (size_t)bt0 * H_;
    const float* E1 = E0 + H_;
    float acc0 = 0.f, acc1 = 0.f;
    if (act) {
        const float4* eq = reinterpret_cast<const float4*>(
                               EWhT4 + (size_t)b * HQ_ * S_ * 4) + s;
#pragma unroll 4
        for (int hq = 0; hq < HQ_; ++hq) {
            const float4 Ew = eq[(size_t)hq * S_];
            const int h = 4 * hq;
#pragma unroll
            for (int j = 0; j < 4; ++j) {
                const float Ewj = j == 0 ? Ew.x : j == 1 ? Ew.y : j == 2 ? Ew.z : Ew.w;
                const float wch = w_c[h + j];
                const float vh = v[h + j];
                float Ec0 = __builtin_amdgcn_exp2f(ck0 * wch);
                float Ec1 = __builtin_amdgcn_exp2f(ck1 * wch);
                float r0 = __builtin_amdgcn_rcpf(fmaf(Ewj * E0[h + j], Ec0, 1.0f));
                float r1 = __builtin_amdgcn_rcpf(fmaf(Ewj * E1[h + j], Ec1, 1.0f));
                acc0 = fmaf(r0, vh, acc0);
                acc1 = fmaf(r1, vh, acc1);
            }
        }
    }

    float e0 = -INFINITY, e1 = -INFINITY;
    if (act) {
        e0 = fminf(fmaxf(sumv - 2.f * acc0, -MAXL), MAXL);
        e1 = fminf(fmaxf(sumv - 2.f * acc1, -MAXL), MAXL);
        if (mask[(size_t)b * S_ + s]) { e0 = -INFINITY; e1 = -INFINITY; }
    }

    float mx0 = wave_max(e0);
    float mx1 = wave_max(e1);
    if (lane == 0) { red[wid] = mx0; red[8 + wid] = mx1; }
    __syncthreads();
    mx0 = fmaxf(fmaxf(fmaxf(red[0], red[1]), fmaxf(red[2], red[3])),
                fmaxf(fmaxf(red[4], red[5]), fmaxf(red[6], red[7])));
    mx1 = fmaxf(fmaxf(fmaxf(red[8], red[9]), fmaxf(red[10], red[11])),
                fmaxf(fmaxf(red[12], red[13]), fmaxf(red[14], red[15])));

    float p0 = act ? __expf(e0 - mx0) : 0.f;
    float p1 = act ? __expf(e1 - mx1) : 0.f;
    float sm0 = wave_sum(p0);
    float sm1 = wave_sum(p1);
    if (lane == 0) { red[16 + wid] = sm0; red[24 + wid] = sm1; }
    __syncthreads();
    sm0 = ((red[16] + red[17]) + (red[18] + red[19])) +
          ((red[20] + red[21]) + (red[22] + red[23]));
    sm1 = ((red[24] + red[25]) + (red[26] + red[27])) +
          ((red[28] + red[29]) + (red[30] + red[31]));

    const float a0 = act ? p0 * __builtin_amdgcn_rcpf(sm0) : 0.f;
    const float a1 = act ? p1 * __builtin_amdgcn_rcpf(sm1) : 0.f;

    // coverage-loss partials for both t (registers only)
    float lp = act ? (fminf(a0, c0) + fminf(a1, c1)) : 0.f;
    lp = wave_sum(lp);
    if (lane == 0) red[wid] = lp;

    if (act) {
        e0_lds[s] = a0;
        e1_lds[s] = a1;
        out[AF_OFF + (size_t)bt0 * S_ + s] = a0;
        out[AF_OFF + (size_t)(bt0 + 1) * S_ + s] = a1;
    }
    __syncthreads();

    if (tid == 0) {
        float tot = ((red[0] + red[1]) + (red[2] + red[3])) +
                    ((red[4] + red[5]) + (red[6] + red[7]));
        atomicAdd(out + LOSS_OFF, tot * (1.0f / (B_ * T_)));
    }

    // context for both t: one enc stream feeds both accumulator sets.
    const int h = tid & (H_ - 1);
    const int half = tid >> 8;           // 0 or 1
    const int sb = half * (S_ / 2);      // 0 or 200
    const float* eb = enc + ((size_t)b * S_ + sb) * H_ + h;
    float q00 = 0.f, q01 = 0.f, q02 = 0.f, q03 = 0.f;
    float q10 = 0.f, q11 = 0.f, q12 = 0.f, q13 = 0.f;
#pragma unroll 5
    for (int j = 0; j < S_ / 2; j += 4) {
        float w0 = eb[(size_t)j * H_];
        float w1 = eb[(size_t)(j + 1) * H_];
        float w2 = eb[(size_t)(j + 2) * H_];
        float w3 = eb[(size_t)(j + 3) * H_];
        q00 = fmaf(e0_lds[sb + j], w0, q00);
        q10 = fmaf(e1_lds[sb + j], w0, q10);
        q01 = fmaf(e0_lds[sb + j + 1], w1, q01);
        q11 = fmaf(e1_lds[sb + j + 1], w1, q11);
        q02 = fmaf(e0_lds[sb + j + 2], w2, q02);
        q12 = fmaf(e1_lds[sb + j + 2], w2, q12);
        q03 = fmaf(e0_lds[sb + j + 3], w3, q03);
        q13 = fmaf(e1_lds[sb + j + 3], w3, q13);
    }
    const float r0 = (q00 + q01) + (q02 + q03);
    const float r1 = (q10 + q11) + (q12 + q13);
    if (half == 0) { ctx0[h] = r0; ctx1[h] = r1; }
    __syncthreads();
    if (half == 1) {
        out[(size_t)bt0 * H_ + h] = ctx0[h] + r0;
        out[(size_t)(bt0 + 1) * H_ + h] = ctx1[h] + r1;
    }
}

extern "C" void kernel_launch(void* const* d_in, const int* in_sizes, int n_in,
                              void* d_out, int out_size, void* d_ws, size_t ws_size,
                              hipStream_t stream) {
    const float* dec = (const float*)d_in[0];
    const float* enc = (const float*)d_in[1];
    const unsigned char* mask = (const unsigned char*)d_in[2];
    const float* W_h = (const float*)d_in[3];
    const float* W_s = (const float*)d_in[4];
    const float* w_c = (const float*)d_in[5];
    const float* v = (const float*)d_in[6];
    const float* b_attn = (const float*)d_in[7];

    float* out = (float*)d_out;
    float* ws = (float*)d_ws;
    float* EWhT4 = ws + EWHT_OFF;
    float* EWsb = ws + EWSB_OFF;
    float* Acov = ws + ACOV_OFF;

    const int nb_gemm = (B_ * S_) / ROWS + BT_ / ROWS;  // 400 + 100
    const int nb_pair = B_ * (T_ / 2);                  // 400
    k_gemm<<<nb_gemm, 256, 0, stream>>>(dec, enc, W_h, W_s, b_attn, EWhT4, EWsb);
    k_prelim<<<nb_pair, 512, 0, stream>>>(EWhT4, EWsb, v, mask, Acov);
    k_cumsum<<<(B_ * S_ + 63) / 64, 64, 0, stream>>>(Acov, out);
    k_final<<<nb_pair, 512, 0, stream>>>(EWhT4, EWsb, v, w_c, Acov, mask, enc, out);
}